// Round 4
// baseline (922.124 us; speedup 1.0000x reference)
//
#include <hip/hip_runtime.h>
#include <hip/hip_bf16.h>
#include <stdint.h>

#define NEXP 8
#define NROWS 8192
#define HID 2048
#define INTERN 2048
#define CAP 8192
#define KDIM 2048

typedef __attribute__((ext_vector_type(4))) float f32x4;
typedef __attribute__((ext_vector_type(8))) short bf16x8;

__device__ __forceinline__ unsigned short f2bf(float f) {
  union { float f; uint32_t u; } v; v.f = f;
  uint32_t u = v.u;
  uint32_t r = (u + 0x7fffu + ((u >> 16) & 1u)) >> 16;
  return (unsigned short)r;
}
__device__ __forceinline__ float bf2f(unsigned short u) {
  union { uint32_t u; float f; } v; v.u = (uint32_t)u << 16; return v.f;
}
__device__ __forceinline__ void gload16(const unsigned short* g, char* l) {
  __builtin_amdgcn_global_load_lds((const __attribute__((address_space(1))) void*)g,
                                   (__attribute__((address_space(3))) void*)l,
                                   16, 0, 0);
}

// ---------------- x fp32 -> bf16 ----------------
__global__ __launch_bounds__(256) void xcast_kernel(const float* __restrict__ x,
                                                    unsigned short* __restrict__ xb) {
  size_t i = ((size_t)blockIdx.x * 256 + threadIdx.x) * 8;
  size_t stride = (size_t)gridDim.x * 256 * 8;
  const size_t tot = (size_t)NROWS * HID;
  for (; i < tot; i += stride) {
    float4 a = *reinterpret_cast<const float4*>(x + i);
    float4 b = *reinterpret_cast<const float4*>(x + i + 4);
    unsigned short u[8];
    u[0] = f2bf(a.x); u[1] = f2bf(a.y); u[2] = f2bf(a.z); u[3] = f2bf(a.w);
    u[4] = f2bf(b.x); u[5] = f2bf(b.y); u[6] = f2bf(b.z); u[7] = f2bf(b.w);
    *reinterpret_cast<int4*>(xb + i) = *reinterpret_cast<const int4*>(u);
  }
}

// ---------------- router ----------------
__global__ void router_kernel(const float* __restrict__ probs,
                              int* __restrict__ cnt,
                              int* __restrict__ brow,
                              float* __restrict__ bw) {
  int row = blockIdx.x * blockDim.x + threadIdx.x;
  if (row >= NROWS) return;
  float p[8];
#pragma unroll
  for (int j = 0; j < 8; j++) p[j] = probs[row * 8 + j];
  int i1 = 0; float v1 = p[0];
#pragma unroll
  for (int j = 1; j < 8; j++) if (p[j] > v1) { v1 = p[j]; i1 = j; }
  int i2 = -1; float v2 = -1e30f;
#pragma unroll
  for (int j = 0; j < 8; j++) if (j != i1 && p[j] > v2) { v2 = p[j]; i2 = j; }
  float s = v1 + v2;
  float w1 = v1 / s, w2 = v2 / s;
  int pos1 = atomicAdd(&cnt[i1], 1);
  brow[i1 * CAP + pos1] = row; bw[i1 * CAP + pos1] = w1;
  int pos2 = atomicAdd(&cnt[i2], 1);
  brow[i2 * CAP + pos2] = row; bw[i2 * CAP + pos2] = w2;
}

__global__ void offsets_kernel(const int* __restrict__ cnt, int* __restrict__ ofs) {
  if (threadIdx.x == 0 && blockIdx.x == 0) {
    int a = 0;
    for (int e = 0; e < NEXP; e++) { ofs[e] = a; a += cnt[e]; }
  }
}

// ---------------- transpose+cast: [E][K][N] f32 -> [E][N][K] bf16 ----------------
__global__ __launch_bounds__(256) void transpose_cast_kernel(const float* __restrict__ src,
                                                             unsigned short* __restrict__ dst) {
  __shared__ float tile[64][65];
  const int e = blockIdx.z;
  const int k0 = blockIdx.y * 64;
  const int n0 = blockIdx.x * 64;
  const float* s = src + (size_t)e * KDIM * KDIM;
  unsigned short* d = dst + (size_t)e * KDIM * KDIM;
  const int t = threadIdx.x;
  const int rr = t >> 4, cc = (t & 15) * 4;
#pragma unroll
  for (int i = 0; i < 4; i++) {
    float4 v = *reinterpret_cast<const float4*>(s + (size_t)(k0 + rr + i * 16) * KDIM + n0 + cc);
    tile[rr + i * 16][cc + 0] = v.x; tile[rr + i * 16][cc + 1] = v.y;
    tile[rr + i * 16][cc + 2] = v.z; tile[rr + i * 16][cc + 3] = v.w;
  }
  __syncthreads();
  const int n = t >> 2, kk0 = (t & 3) * 16;
  unsigned short u[16];
#pragma unroll
  for (int j = 0; j < 16; j++) u[j] = f2bf(tile[kk0 + j][n]);
  *reinterpret_cast<int4*>(d + (size_t)(n0 + n) * KDIM + k0 + kk0 + 0) = *reinterpret_cast<const int4*>(&u[0]);
  *reinterpret_cast<int4*>(d + (size_t)(n0 + n) * KDIM + k0 + kk0 + 8) = *reinterpret_cast<const int4*>(&u[8]);
}

// ---------------- 256x256 grouped GEMM, BK=64, 8-phase (m201 template) ----------------
// 512 thr = 8 waves (2M x 4N). LDS: 2 bufs x {A0,A1,B0,B1} half-tile slots x 16KB = 128KB.
// Per-wave frags: rows (mi>>2)*128 + wm*64 + (mi&3)*16, cols (ni>>1)*128 + wn*32 + (ni&1)*16
// -> each phase (ah,bh) touches exactly A-slot ah + B-slot bh (16 MFMA over K=64).
// Stage schedule (1 half-tile = 2 gload16/thread per phase), slot freed >=1 phase before:
//   ph1:Ao1(t2k+1) ph2:Bo1 ph3:Ae0(t2k+2) ph4:Be0+VMC4 ph5:Ae1 ph6:Be1 ph7:Ao0(t2k+3) ph8:Bo0+VMC4
// vmcnt(4) ledger: ph4-wait drains {Ao0',Bo0',Ao1,Bo1} (needed ph5-7), leaves {Ae0,Be0};
//                  ph8-wait drains {Ae0,Be0,Ae1,Be1} (needed next ph1-3), leaves {Ao0,Bo0}.
// LDS swizzle: phys_kbyte = kbyte ^ ((row&7)<<4); both-sides (pre-swizzled global src).
template <int EPI>
__global__ __launch_bounds__(512, 2)
void gemm8p_kernel(const unsigned short* __restrict__ A,
                   const unsigned short* __restrict__ W,
                   const int* __restrict__ cnt, const int* __restrict__ ofs,
                   const int* __restrict__ brow, const float* __restrict__ bw,
                   unsigned short* __restrict__ hbuf,
                   float* __restrict__ out) {
  const int e = blockIdx.z, mt = blockIdx.y, nt = blockIdx.x;
  const int Me = cnt[e];
  if (mt * 256 >= Me) return;
  __shared__ unsigned short lds[65536];   // 128 KiB
  __shared__ int ridx[256];
  __shared__ float rww[256];
  const int t = threadIdx.x, lane = t & 63, w = t >> 6;
  const int oe = ofs[e];
  if (t < 256) {
    int sl = mt * 256 + t;
    int ok = sl < Me;
    ridx[t] = ok ? brow[e * CAP + sl] : 0;
    rww[t] = ok ? bw[e * CAP + sl] : 0.f;
  }
  __syncthreads();

  const int wm = w >> 2, wn = w & 3;
  const int l15 = lane & 15, kq = lane >> 4;
  char* ldsb = (char*)lds;
  const int wdst = w * 1024;

  // ---- staging per-thread global pointers (pre-swizzled k)
  const int srow = t >> 3;                     // 0..63 within 64-row chunk
  const int kg = ((t & 7) ^ (srow & 7)) * 8;   // swizzled k elem offset
  const unsigned short *pA00, *pA01, *pA10, *pA11;
  if (EPI == 2) {
    int s;
    s = mt * 256 +   0 + srow; if (s >= Me) s = 0; pA00 = A + (size_t)(oe + s) * KDIM + kg;
    s = mt * 256 +  64 + srow; if (s >= Me) s = 0; pA01 = A + (size_t)(oe + s) * KDIM + kg;
    s = mt * 256 + 128 + srow; if (s >= Me) s = 0; pA10 = A + (size_t)(oe + s) * KDIM + kg;
    s = mt * 256 + 192 + srow; if (s >= Me) s = 0; pA11 = A + (size_t)(oe + s) * KDIM + kg;
  } else {
    pA00 = A + (size_t)ridx[  0 + srow] * KDIM + kg;
    pA01 = A + (size_t)ridx[ 64 + srow] * KDIM + kg;
    pA10 = A + (size_t)ridx[128 + srow] * KDIM + kg;
    pA11 = A + (size_t)ridx[192 + srow] * KDIM + kg;
  }
  const unsigned short* Wb = W + (size_t)e * KDIM * KDIM;
  const unsigned short* pB00 = Wb + (size_t)(nt * 256 +   0 + srow) * KDIM + kg;
  const unsigned short* pB01 = Wb + (size_t)(nt * 256 +  64 + srow) * KDIM + kg;
  const unsigned short* pB10 = Wb + (size_t)(nt * 256 + 128 + srow) * KDIM + kg;
  const unsigned short* pB11 = Wb + (size_t)(nt * 256 + 192 + srow) * KDIM + kg;

  // ---- ds_read offsets
  const int aoff = (wm * 64 + l15) * 128;
  const int boff = 32768 + (wn * 32 + l15) * 128;
  const int c0 = (kq * 16) ^ ((l15 & 7) << 4);

  f32x4 acc[8][4] = {};
  bf16x8 afr[8], bfr[4];

#define STG_A(h, buf, koff) do { \
    char* d_ = ldsb + (buf) * 65536 + (h) * 16384 + wdst; \
    gload16(pA##h##0 + (koff), d_); \
    gload16(pA##h##1 + (koff), d_ + 8192); } while (0)
#define STG_B(h, buf, koff) do { \
    char* d_ = ldsb + (buf) * 65536 + 32768 + (h) * 16384 + wdst; \
    gload16(pB##h##0 + (koff), d_); \
    gload16(pB##h##1 + (koff), d_ + 8192); } while (0)
#define LA(buf, ah) do { \
    const char* ab_ = ldsb + (buf) * 65536 + (ah) * 16384 + aoff; \
    _Pragma("unroll") for (int mi_ = 0; mi_ < 4; mi_++) { \
      afr[mi_ * 2 + 0] = *reinterpret_cast<const bf16x8*>(ab_ + mi_ * 2048 + c0); \
      afr[mi_ * 2 + 1] = *reinterpret_cast<const bf16x8*>(ab_ + mi_ * 2048 + (c0 ^ 64)); } } while (0)
#define LB(buf, bh) do { \
    const char* bb_ = ldsb + (buf) * 65536 + (bh) * 16384 + boff; \
    _Pragma("unroll") for (int ni_ = 0; ni_ < 2; ni_++) { \
      bfr[ni_ * 2 + 0] = *reinterpret_cast<const bf16x8*>(bb_ + ni_ * 2048 + c0); \
      bfr[ni_ * 2 + 1] = *reinterpret_cast<const bf16x8*>(bb_ + ni_ * 2048 + (c0 ^ 64)); } } while (0)
#define MM(ah, bh) do { \
    __builtin_amdgcn_s_setprio(1); \
    _Pragma("unroll") for (int ks_ = 0; ks_ < 2; ks_++) \
    _Pragma("unroll") for (int mi_ = 0; mi_ < 4; mi_++) \
    _Pragma("unroll") for (int ni_ = 0; ni_ < 2; ni_++) \
      acc[(ah) * 4 + mi_][(bh) * 2 + ni_] = __builtin_amdgcn_mfma_f32_16x16x32_bf16( \
          afr[mi_ * 2 + ks_], bfr[ni_ * 2 + ks_], acc[(ah) * 4 + mi_][(bh) * 2 + ni_], 0, 0, 0); \
    __builtin_amdgcn_s_setprio(0); } while (0)
#define BARR asm volatile("s_barrier" ::: "memory")
#define LGKM0 asm volatile("s_waitcnt lgkmcnt(0)" ::: "memory")
#define VMC(n) asm volatile("s_waitcnt vmcnt(" #n ")" ::: "memory")

  // prologue: tile0 (even buf) fully + tile1 A0,B0; leave last 4 loads in flight
  STG_A(0, 0, 0); STG_B(0, 0, 0); STG_A(1, 0, 0); STG_B(1, 0, 0);
  STG_A(0, 1, 64); STG_B(0, 1, 64);
  VMC(4); BARR;

  for (int kt = 0; kt < 15; ++kt) {
    const int k1 = (2 * kt + 1) * 64, k2 = (2 * kt + 2) * 64, k3 = (2 * kt + 3) * 64;
    LA(0, 0); LB(0, 0); STG_A(1, 1, k1);         BARR; LGKM0; MM(0, 0); BARR;  // ph1
    LB(0, 1);           STG_B(1, 1, k1);         BARR; LGKM0; MM(0, 1); BARR;  // ph2
    LA(0, 1); LB(0, 0); STG_A(0, 0, k2);         BARR; LGKM0; MM(1, 0); BARR;  // ph3
    LB(0, 1);           STG_B(0, 0, k2); VMC(4); BARR; LGKM0; MM(1, 1); BARR;  // ph4
    LA(1, 0); LB(1, 0); STG_A(1, 0, k2);         BARR; LGKM0; MM(0, 0); BARR;  // ph5
    LB(1, 1);           STG_B(1, 0, k2);         BARR; LGKM0; MM(0, 1); BARR;  // ph6
    LA(1, 1); LB(1, 0); STG_A(0, 1, k3);         BARR; LGKM0; MM(1, 0); BARR;  // ph7
    LB(1, 1);           STG_B(0, 1, k3); VMC(4); BARR; LGKM0; MM(1, 1); BARR;  // ph8
  }
  {  // tail iteration: tiles 30,31; stage only tile 31 (ph1-2); drain at ph4
    const int k1 = 31 * 64;
    LA(0, 0); LB(0, 0); STG_A(1, 1, k1); BARR; LGKM0; MM(0, 0); BARR;
    LB(0, 1);           STG_B(1, 1, k1); BARR; LGKM0; MM(0, 1); BARR;
    LA(0, 1); LB(0, 0);                  BARR; LGKM0; MM(1, 0); BARR;
    LB(0, 1);                    VMC(0); BARR; LGKM0; MM(1, 1); BARR;
    LA(1, 0); LB(1, 0);                  BARR; LGKM0; MM(0, 0); BARR;
    LB(1, 1);                            BARR; LGKM0; MM(0, 1); BARR;
    LA(1, 1); LB(1, 0);                  BARR; LGKM0; MM(1, 0); BARR;
    LB(1, 1);                            BARR; LGKM0; MM(1, 1); BARR;
  }
#undef STG_A
#undef STG_B
#undef LA
#undef LB
#undef MM
#undef BARR
#undef LGKM0
#undef VMC

  const int mrem = Me - mt * 256;
#pragma unroll
  for (int mi = 0; mi < 8; mi++) {
    const int lrow0 = (mi >> 2) * 128 + wm * 64 + (mi & 3) * 16 + kq * 4;
#pragma unroll
    for (int ni = 0; ni < 4; ni++) {
      const int coln = nt * 256 + (ni >> 1) * 128 + wn * 32 + (ni & 1) * 16 + l15;
#pragma unroll
      for (int r = 0; r < 4; r++) {
        const int lrow = lrow0 + r;
        if (lrow < mrem) {
          if (EPI == 0) {
            hbuf[(size_t)(oe + mt * 256 + lrow) * KDIM + coln] = f2bf(acc[mi][ni][r]);
          } else if (EPI == 1) {
            size_t idx = (size_t)(oe + mt * 256 + lrow) * KDIM + coln;
            float h1 = bf2f(hbuf[idx]);
            float sig = 1.f / (1.f + __expf(-h1));
            hbuf[idx] = f2bf(h1 * sig * acc[mi][ni][r]);
          } else {
            float v = acc[mi][ni][r] * rww[lrow];
            unsafeAtomicAdd(&out[(size_t)ridx[lrow] * HID + coln], v);
          }
        }
      }
    }
  }
}

extern "C" void kernel_launch(void* const* d_in, const int* in_sizes, int n_in,
                              void* d_out, int out_size, void* d_ws, size_t ws_size,
                              hipStream_t stream) {
  const float* x     = (const float*)d_in[0];
  const float* probs = (const float*)d_in[1];
  const float* fc1   = (const float*)d_in[2];
  const float* fc2   = (const float*)d_in[3];
  const float* fc3   = (const float*)d_in[4];
  float* out = (float*)d_out;

  char* ws = (char*)d_ws;
  const size_t WSZ = (size_t)NEXP * HID * INTERN * 2;  // 64 MiB per weight tensor
  unsigned short* wt1 = (unsigned short*)(ws);
  unsigned short* wt3 = (unsigned short*)(ws + WSZ);
  unsigned short* wt2 = (unsigned short*)(ws + 2 * WSZ);
  unsigned short* h1  = (unsigned short*)(ws + 3 * WSZ);   // 16384 x 2048 bf16
  unsigned short* xb  = (unsigned short*)(ws + 4 * WSZ);   // 8192 x 2048 bf16
  char* rbase = ws + 4 * WSZ + (size_t)NROWS * HID * 2;
  int*   brow = (int*)  (rbase);
  float* bw   = (float*)(rbase + (size_t)NEXP * CAP * 4);
  int*   cnt  = (int*)  (rbase + 2 * (size_t)NEXP * CAP * 4);
  int*   ofs  = (int*)  (rbase + 2 * (size_t)NEXP * CAP * 4 + 64);

  hipMemsetAsync(d_out, 0, (size_t)out_size * sizeof(float), stream);
  hipMemsetAsync(cnt, 0, 64, stream);

  xcast_kernel<<<2048, 256, 0, stream>>>(x, xb);
  transpose_cast_kernel<<<dim3(32, 32, 8), 256, 0, stream>>>(fc1, wt1);
  transpose_cast_kernel<<<dim3(32, 32, 8), 256, 0, stream>>>(fc3, wt3);
  transpose_cast_kernel<<<dim3(32, 32, 8), 256, 0, stream>>>(fc2, wt2);
  router_kernel<<<NROWS / 256, 256, 0, stream>>>(probs, cnt, brow, bw);
  offsets_kernel<<<1, 64, 0, stream>>>(cnt, ofs);

  gemm8p_kernel<0><<<dim3(INTERN / 256, CAP / 256, NEXP), 512, 0, stream>>>(xb, wt1, cnt, ofs, brow, bw, h1, out);
  gemm8p_kernel<1><<<dim3(INTERN / 256, CAP / 256, NEXP), 512, 0, stream>>>(xb, wt3, cnt, ofs, brow, bw, h1, out);
  gemm8p_kernel<2><<<dim3(HID / 256, CAP / 256, NEXP), 512, 0, stream>>>(h1, wt2, cnt, ofs, brow, bw, h1, out);
}

// Round 5
// 781.602 us; speedup vs baseline: 1.1798x; 1.1798x over previous
//
#include <hip/hip_runtime.h>
#include <hip/hip_bf16.h>
#include <stdint.h>

#define NEXP 8
#define NROWS 8192
#define HID 2048
#define INTERN 2048
#define CAP 8192
#define KDIM 2048

typedef __attribute__((ext_vector_type(4))) float f32x4;
typedef __attribute__((ext_vector_type(8))) short bf16x8;

__device__ __forceinline__ unsigned short f2bf(float f) {
  union { float f; uint32_t u; } v; v.f = f;
  uint32_t u = v.u;
  uint32_t r = (u + 0x7fffu + ((u >> 16) & 1u)) >> 16;
  return (unsigned short)r;
}
__device__ __forceinline__ float bf2f(unsigned short u) {
  union { uint32_t u; float f; } v; v.u = (uint32_t)u << 16; return v.f;
}
__device__ __forceinline__ void gload16(const unsigned short* g, char* l) {
  __builtin_amdgcn_global_load_lds((const __attribute__((address_space(1))) void*)g,
                                   (__attribute__((address_space(3))) void*)l,
                                   16, 0, 0);
}

// ---------------- x fp32 -> bf16 ----------------
__global__ __launch_bounds__(256) void xcast_kernel(const float* __restrict__ x,
                                                    unsigned short* __restrict__ xb) {
  size_t i = ((size_t)blockIdx.x * 256 + threadIdx.x) * 8;
  size_t stride = (size_t)gridDim.x * 256 * 8;
  const size_t tot = (size_t)NROWS * HID;
  for (; i < tot; i += stride) {
    float4 a = *reinterpret_cast<const float4*>(x + i);
    float4 b = *reinterpret_cast<const float4*>(x + i + 4);
    unsigned short u[8];
    u[0] = f2bf(a.x); u[1] = f2bf(a.y); u[2] = f2bf(a.z); u[3] = f2bf(a.w);
    u[4] = f2bf(b.x); u[5] = f2bf(b.y); u[6] = f2bf(b.z); u[7] = f2bf(b.w);
    *reinterpret_cast<int4*>(xb + i) = *reinterpret_cast<const int4*>(u);
  }
}

// ---------------- router: top-2 of 8, renormalize, bucket per expert ----------------
__global__ void router_kernel(const float* __restrict__ probs,
                              int* __restrict__ cnt,
                              int* __restrict__ brow,
                              float* __restrict__ bw) {
  int row = blockIdx.x * blockDim.x + threadIdx.x;
  if (row >= NROWS) return;
  float p[8];
#pragma unroll
  for (int j = 0; j < 8; j++) p[j] = probs[row * 8 + j];
  int i1 = 0; float v1 = p[0];
#pragma unroll
  for (int j = 1; j < 8; j++) if (p[j] > v1) { v1 = p[j]; i1 = j; }
  int i2 = -1; float v2 = -1e30f;
#pragma unroll
  for (int j = 0; j < 8; j++) if (j != i1 && p[j] > v2) { v2 = p[j]; i2 = j; }
  float s = v1 + v2;
  float w1 = v1 / s, w2 = v2 / s;
  int pos1 = atomicAdd(&cnt[i1], 1);
  brow[i1 * CAP + pos1] = row; bw[i1 * CAP + pos1] = w1;
  int pos2 = atomicAdd(&cnt[i2], 1);
  brow[i2 * CAP + pos2] = row; bw[i2 * CAP + pos2] = w2;
}

__global__ void offsets_kernel(const int* __restrict__ cnt, int* __restrict__ ofs) {
  if (threadIdx.x == 0 && blockIdx.x == 0) {
    int a = 0;
    for (int e = 0; e < NEXP; e++) { ofs[e] = a; a += cnt[e]; }
  }
}

// ---------------- transpose+cast: [E][K][N] f32 -> [E][N][K] bf16, 64x64 tiles ----------------
__global__ __launch_bounds__(256) void transpose_cast_kernel(const float* __restrict__ src,
                                                             unsigned short* __restrict__ dst) {
  __shared__ float tile[64][65];
  const int e = blockIdx.z;
  const int k0 = blockIdx.y * 64;
  const int n0 = blockIdx.x * 64;
  const float* s = src + (size_t)e * KDIM * KDIM;
  unsigned short* d = dst + (size_t)e * KDIM * KDIM;
  const int t = threadIdx.x;
  const int rr = t >> 4, cc = (t & 15) * 4;
#pragma unroll
  for (int i = 0; i < 4; i++) {
    float4 v = *reinterpret_cast<const float4*>(s + (size_t)(k0 + rr + i * 16) * KDIM + n0 + cc);
    tile[rr + i * 16][cc + 0] = v.x; tile[rr + i * 16][cc + 1] = v.y;
    tile[rr + i * 16][cc + 2] = v.z; tile[rr + i * 16][cc + 3] = v.w;
  }
  __syncthreads();
  const int n = t >> 2, kk0 = (t & 3) * 16;
  unsigned short u[16];
#pragma unroll
  for (int j = 0; j < 16; j++) u[j] = f2bf(tile[kk0 + j][n]);
  *reinterpret_cast<int4*>(d + (size_t)(n0 + n) * KDIM + k0 + kk0 + 0) = *reinterpret_cast<const int4*>(&u[0]);
  *reinterpret_cast<int4*>(d + (size_t)(n0 + n) * KDIM + k0 + kk0 + 8) = *reinterpret_cast<const int4*>(&u[8]);
}

// ---------------- m97-structure GEMM, 128x128 tile, BK=64, global_load_lds, swizzled LDS ----
// Round-2 proven structure; BK doubled 32->64 so the per-K-step barrier/vmcnt(0) drain is
// amortized over 32 MFMA instead of 16. LDS stays 32 KB (A 16K + B 16K) -> 3-4 blocks/CU.
// Swizzle (128B rows): phys 16B-slot j = logical_slot ^ (row&7); applied BOTH sides
// (pre-swizzled per-lane global source for global_load_lds; XOR'd ds_read offset).
// EPI 0: hbuf = bf16(acc)                      (fc1 -> h1)
// EPI 1: hbuf = bf16(silu(h1)*acc) in-place    (fc3 -> act)
// EPI 2: out[token] += rw * acc (atomic)       (fc2)
template <int EPI>
__global__ __launch_bounds__(256, 2)
void gemm_kernel(const unsigned short* __restrict__ A,
                 const unsigned short* __restrict__ W,
                 const int* __restrict__ cnt, const int* __restrict__ ofs,
                 const int* __restrict__ brow, const float* __restrict__ bw,
                 unsigned short* __restrict__ hbuf,
                 float* __restrict__ out) {
  const int e = blockIdx.z, mt = blockIdx.y, nt = blockIdx.x;
  const int Me = cnt[e];
  if (mt * 128 >= Me) return;
  __shared__ unsigned short As[128 * 64];   // 16 KB
  __shared__ unsigned short Bs[128 * 64];   // 16 KB
  __shared__ int ridx[128];
  __shared__ float rww[128];
  const int t = threadIdx.x, lane = t & 63, wave = t >> 6;
  const int oe = ofs[e];
  if (t < 128) {
    int sl = mt * 128 + t;
    int ok = sl < Me;
    ridx[t] = ok ? brow[e * CAP + sl] : 0;
    rww[t] = ok ? bw[e * CAP + sl] : 0.f;
  }
  __syncthreads();

  // ---- staging: thread t covers rows {srow, +32, +64, +96}, 16B slot (t&7) of each row.
  // LDS slot j of row r holds global k-slot j ^ (r&7)  (involution, rule #21).
  const int srow = t >> 3;           // 0..31
  const int jslot = t & 7;
  const int kg = (jslot ^ (srow & 7)) * 8;   // pre-swizzled global k elem offset
  const unsigned short *pA0, *pA1, *pA2, *pA3;
  if (EPI == 2) {
    int s;
    s = mt * 128 + srow +  0; if (s >= Me) s = 0; pA0 = A + (size_t)(oe + s) * KDIM + kg;
    s = mt * 128 + srow + 32; if (s >= Me) s = 0; pA1 = A + (size_t)(oe + s) * KDIM + kg;
    s = mt * 128 + srow + 64; if (s >= Me) s = 0; pA2 = A + (size_t)(oe + s) * KDIM + kg;
    s = mt * 128 + srow + 96; if (s >= Me) s = 0; pA3 = A + (size_t)(oe + s) * KDIM + kg;
  } else {
    pA0 = A + (size_t)ridx[srow +  0] * KDIM + kg;
    pA1 = A + (size_t)ridx[srow + 32] * KDIM + kg;
    pA2 = A + (size_t)ridx[srow + 64] * KDIM + kg;
    pA3 = A + (size_t)ridx[srow + 96] * KDIM + kg;
  }
  const unsigned short* Wb = W + (size_t)e * KDIM * KDIM;
  const unsigned short* pB0 = Wb + (size_t)(nt * 128 + srow +  0) * KDIM + kg;
  const unsigned short* pB1 = Wb + (size_t)(nt * 128 + srow + 32) * KDIM + kg;
  const unsigned short* pB2 = Wb + (size_t)(nt * 128 + srow + 64) * KDIM + kg;
  const unsigned short* pB3 = Wb + (size_t)(nt * 128 + srow + 96) * KDIM + kg;
  // per-wave-uniform LDS dest bases (lane*16 added by HW)
  char* dA = (char*)As + wave * 1024;
  char* dB = (char*)Bs + wave * 1024;

  // ---- ds_read fragment offsets (swizzled); row stride 128 B
  const int wm = wave >> 1, wn = wave & 1;
  const int l15 = lane & 15, kq = lane >> 4;
  const int c0 = (kq * 16) ^ ((l15 & 7) << 4);
  const int aoff = (wm * 64 + l15) * 128;
  const int boff = (wn * 64 + l15) * 128;

  f32x4 acc[4][4] = {};

  for (int k0 = 0; k0 < KDIM; k0 += 64) {
    gload16(pA0, dA);         gload16(pA1, dA + 4096);
    gload16(pA2, dA + 8192);  gload16(pA3, dA + 12288);
    gload16(pB0, dB);         gload16(pB1, dB + 4096);
    gload16(pB2, dB + 8192);  gload16(pB3, dB + 12288);
    pA0 += 64; pA1 += 64; pA2 += 64; pA3 += 64;
    pB0 += 64; pB1 += 64; pB2 += 64; pB3 += 64;
    __syncthreads();   // compiler drains vmcnt(0) here (m97 structural stall, now per 64-K)

    bf16x8 af0[4], bf0[4], af1[4], bf1[4];
#pragma unroll
    for (int i = 0; i < 4; i++) {
      af0[i] = *reinterpret_cast<const bf16x8*>((const char*)As + aoff + i * 2048 + c0);
      bf0[i] = *reinterpret_cast<const bf16x8*>((const char*)Bs + boff + i * 2048 + c0);
    }
#pragma unroll
    for (int mi = 0; mi < 4; mi++)
#pragma unroll
      for (int ni = 0; ni < 4; ni++)
        acc[mi][ni] = __builtin_amdgcn_mfma_f32_16x16x32_bf16(af0[mi], bf0[ni], acc[mi][ni], 0, 0, 0);
#pragma unroll
    for (int i = 0; i < 4; i++) {
      af1[i] = *reinterpret_cast<const bf16x8*>((const char*)As + aoff + i * 2048 + (c0 ^ 64));
      bf1[i] = *reinterpret_cast<const bf16x8*>((const char*)Bs + boff + i * 2048 + (c0 ^ 64));
    }
#pragma unroll
    for (int mi = 0; mi < 4; mi++)
#pragma unroll
      for (int ni = 0; ni < 4; ni++)
        acc[mi][ni] = __builtin_amdgcn_mfma_f32_16x16x32_bf16(af1[mi], bf1[ni], acc[mi][ni], 0, 0, 0);
    __syncthreads();
  }

  const int slot0 = oe + mt * 128;
#pragma unroll
  for (int mi = 0; mi < 4; mi++) {
#pragma unroll
    for (int ni = 0; ni < 4; ni++) {
      const int coln = nt * 128 + wn * 64 + ni * 16 + l15;
#pragma unroll
      for (int r = 0; r < 4; r++) {
        const int lrow = wm * 64 + mi * 16 + kq * 4 + r;
        if (mt * 128 + lrow < Me) {
          if (EPI == 0) {
            hbuf[(size_t)(slot0 + lrow) * KDIM + coln] = f2bf(acc[mi][ni][r]);
          } else if (EPI == 1) {
            size_t idx = (size_t)(slot0 + lrow) * KDIM + coln;
            float h1 = bf2f(hbuf[idx]);
            float sig = 1.f / (1.f + __expf(-h1));
            hbuf[idx] = f2bf(h1 * sig * acc[mi][ni][r]);
          } else {
            float v = acc[mi][ni][r] * rww[lrow];
            unsafeAtomicAdd(&out[(size_t)ridx[lrow] * HID + coln], v);
          }
        }
      }
    }
  }
}

extern "C" void kernel_launch(void* const* d_in, const int* in_sizes, int n_in,
                              void* d_out, int out_size, void* d_ws, size_t ws_size,
                              hipStream_t stream) {
  const float* x     = (const float*)d_in[0];
  const float* probs = (const float*)d_in[1];
  const float* fc1   = (const float*)d_in[2];
  const float* fc2   = (const float*)d_in[3];
  const float* fc3   = (const float*)d_in[4];
  float* out = (float*)d_out;

  char* ws = (char*)d_ws;
  const size_t WSZ = (size_t)NEXP * HID * INTERN * 2;  // 64 MiB per weight tensor
  unsigned short* wt1 = (unsigned short*)(ws);
  unsigned short* wt3 = (unsigned short*)(ws + WSZ);
  unsigned short* wt2 = (unsigned short*)(ws + 2 * WSZ);
  unsigned short* h1  = (unsigned short*)(ws + 3 * WSZ);   // 16384 x 2048 bf16 (h1, then act)
  unsigned short* xb  = (unsigned short*)(ws + 4 * WSZ);   // 8192 x 2048 bf16
  char* rbase = ws + 4 * WSZ + (size_t)NROWS * HID * 2;
  int*   brow = (int*)  (rbase);
  float* bw   = (float*)(rbase + (size_t)NEXP * CAP * 4);
  int*   cnt  = (int*)  (rbase + 2 * (size_t)NEXP * CAP * 4);
  int*   ofs  = (int*)  (rbase + 2 * (size_t)NEXP * CAP * 4 + 64);

  hipMemsetAsync(d_out, 0, (size_t)out_size * sizeof(float), stream);
  hipMemsetAsync(cnt, 0, 64, stream);

  xcast_kernel<<<2048, 256, 0, stream>>>(x, xb);
  transpose_cast_kernel<<<dim3(32, 32, 8), 256, 0, stream>>>(fc1, wt1);
  transpose_cast_kernel<<<dim3(32, 32, 8), 256, 0, stream>>>(fc3, wt3);
  transpose_cast_kernel<<<dim3(32, 32, 8), 256, 0, stream>>>(fc2, wt2);
  router_kernel<<<NROWS / 256, 256, 0, stream>>>(probs, cnt, brow, bw);
  offsets_kernel<<<1, 64, 0, stream>>>(cnt, ofs);

  gemm_kernel<0><<<dim3(INTERN / 128, CAP / 128, NEXP), 256, 0, stream>>>(xb, wt1, cnt, ofs, brow, bw, h1, out);
  gemm_kernel<1><<<dim3(INTERN / 128, CAP / 128, NEXP), 256, 0, stream>>>(xb, wt3, cnt, ofs, brow, bw, h1, out);
  gemm_kernel<2><<<dim3(HID / 128, CAP / 128, NEXP), 256, 0, stream>>>(h1, wt2, cnt, ofs, brow, bw, h1, out);
}

// Round 6
// 731.295 us; speedup vs baseline: 1.2609x; 1.0688x over previous
//
#include <hip/hip_runtime.h>
#include <hip/hip_bf16.h>
#include <stdint.h>

#define NEXP 8
#define NROWS 8192
#define HID 2048
#define INTERN 2048
#define CAP 8192
#define KDIM 2048

typedef __attribute__((ext_vector_type(4))) float f32x4;
typedef __attribute__((ext_vector_type(8))) short bf16x8;

__device__ __forceinline__ unsigned short f2bf(float f) {
  union { float f; uint32_t u; } v; v.f = f;
  uint32_t u = v.u;
  uint32_t r = (u + 0x7fffu + ((u >> 16) & 1u)) >> 16;
  return (unsigned short)r;
}
__device__ __forceinline__ float bf2f(unsigned short u) {
  union { uint32_t u; float f; } v; v.u = (uint32_t)u << 16; return v.f;
}
__device__ __forceinline__ void gload16(const unsigned short* g, char* l) {
  __builtin_amdgcn_global_load_lds((const __attribute__((address_space(1))) void*)g,
                                   (__attribute__((address_space(3))) void*)l,
                                   16, 0, 0);
}

// ---------------- x fp32 -> bf16 ----------------
__global__ __launch_bounds__(256) void xcast_kernel(const float* __restrict__ x,
                                                    unsigned short* __restrict__ xb) {
  size_t i = ((size_t)blockIdx.x * 256 + threadIdx.x) * 8;
  size_t stride = (size_t)gridDim.x * 256 * 8;
  const size_t tot = (size_t)NROWS * HID;
  for (; i < tot; i += stride) {
    float4 a = *reinterpret_cast<const float4*>(x + i);
    float4 b = *reinterpret_cast<const float4*>(x + i + 4);
    unsigned short u[8];
    u[0] = f2bf(a.x); u[1] = f2bf(a.y); u[2] = f2bf(a.z); u[3] = f2bf(a.w);
    u[4] = f2bf(b.x); u[5] = f2bf(b.y); u[6] = f2bf(b.z); u[7] = f2bf(b.w);
    *reinterpret_cast<int4*>(xb + i) = *reinterpret_cast<const int4*>(u);
  }
}

// ---------------- router: top-2 of 8, renormalize, bucket per expert ----------------
__global__ void router_kernel(const float* __restrict__ probs,
                              int* __restrict__ cnt,
                              int* __restrict__ brow,
                              float* __restrict__ bw) {
  int row = blockIdx.x * blockDim.x + threadIdx.x;
  if (row >= NROWS) return;
  float p[8];
#pragma unroll
  for (int j = 0; j < 8; j++) p[j] = probs[row * 8 + j];
  int i1 = 0; float v1 = p[0];
#pragma unroll
  for (int j = 1; j < 8; j++) if (p[j] > v1) { v1 = p[j]; i1 = j; }
  int i2 = -1; float v2 = -1e30f;
#pragma unroll
  for (int j = 0; j < 8; j++) if (j != i1 && p[j] > v2) { v2 = p[j]; i2 = j; }
  float s = v1 + v2;
  float w1 = v1 / s, w2 = v2 / s;
  int pos1 = atomicAdd(&cnt[i1], 1);
  brow[i1 * CAP + pos1] = row; bw[i1 * CAP + pos1] = w1;
  int pos2 = atomicAdd(&cnt[i2], 1);
  brow[i2 * CAP + pos2] = row; bw[i2 * CAP + pos2] = w2;
}

__global__ void offsets_kernel(const int* __restrict__ cnt, int* __restrict__ ofs) {
  if (threadIdx.x == 0 && blockIdx.x == 0) {
    int a = 0;
    for (int e = 0; e < NEXP; e++) { ofs[e] = a; a += cnt[e]; }
  }
}

// ---------------- transpose+cast: [E][K][N] f32 -> [E][N][K] bf16, 64x64 tiles ----------------
__global__ __launch_bounds__(256) void transpose_cast_kernel(const float* __restrict__ src,
                                                             unsigned short* __restrict__ dst) {
  __shared__ float tile[64][65];
  const int e = blockIdx.z;
  const int k0 = blockIdx.y * 64;
  const int n0 = blockIdx.x * 64;
  const float* s = src + (size_t)e * KDIM * KDIM;
  unsigned short* d = dst + (size_t)e * KDIM * KDIM;
  const int t = threadIdx.x;
  const int rr = t >> 4, cc = (t & 15) * 4;
#pragma unroll
  for (int i = 0; i < 4; i++) {
    float4 v = *reinterpret_cast<const float4*>(s + (size_t)(k0 + rr + i * 16) * KDIM + n0 + cc);
    tile[rr + i * 16][cc + 0] = v.x; tile[rr + i * 16][cc + 1] = v.y;
    tile[rr + i * 16][cc + 2] = v.z; tile[rr + i * 16][cc + 3] = v.w;
  }
  __syncthreads();
  const int n = t >> 2, kk0 = (t & 3) * 16;
  unsigned short u[16];
#pragma unroll
  for (int j = 0; j < 16; j++) u[j] = f2bf(tile[kk0 + j][n]);
  *reinterpret_cast<int4*>(d + (size_t)(n0 + n) * KDIM + k0 + kk0 + 0) = *reinterpret_cast<const int4*>(&u[0]);
  *reinterpret_cast<int4*>(d + (size_t)(n0 + n) * KDIM + k0 + kk0 + 8) = *reinterpret_cast<const int4*>(&u[8]);
}

// ---------------- fused GEMM13: act = silu(Xe@fc1) * (Xe@fc3), 128x128 tile, BK=64 ----------
// Round-5 structure, A staged once for BOTH weight matrices; 64 MFMA per 2-barrier K-step.
// Swizzle (128B rows): phys 16B-slot j = logical ^ (row&7); both-sides (rule #21).
__global__ __launch_bounds__(256, 2)
void gemm13_kernel(const unsigned short* __restrict__ A,
                   const unsigned short* __restrict__ W1,
                   const unsigned short* __restrict__ W3,
                   const int* __restrict__ cnt, const int* __restrict__ ofs,
                   const int* __restrict__ brow,
                   unsigned short* __restrict__ act) {
  const int e = blockIdx.z, mt = blockIdx.y, nt = blockIdx.x;
  const int Me = cnt[e];
  if (mt * 128 >= Me) return;
  __shared__ unsigned short As[128 * 64];    // 16 KB
  __shared__ unsigned short B1s[128 * 64];   // 16 KB
  __shared__ unsigned short B3s[128 * 64];   // 16 KB
  __shared__ int ridx[128];
  const int t = threadIdx.x, lane = t & 63, wave = t >> 6;
  const int oe = ofs[e];
  if (t < 128) {
    int sl = mt * 128 + t;
    ridx[t] = (sl < Me) ? brow[e * CAP + sl] : 0;
  }
  __syncthreads();

  const int srow = t >> 3;           // 0..31
  const int kg = ((t & 7) ^ (srow & 7)) * 8;   // pre-swizzled global k elem offset
  const unsigned short* pA0 = A + (size_t)ridx[srow +  0] * KDIM + kg;
  const unsigned short* pA1 = A + (size_t)ridx[srow + 32] * KDIM + kg;
  const unsigned short* pA2 = A + (size_t)ridx[srow + 64] * KDIM + kg;
  const unsigned short* pA3 = A + (size_t)ridx[srow + 96] * KDIM + kg;
  const unsigned short* pB0 = W1 + (size_t)e * KDIM * KDIM + (size_t)(nt * 128 + srow) * KDIM + kg;
  const ptrdiff_t dW = W3 - W1;      // uniform scalar offset between fc1 and fc3
  char* dA  = (char*)As  + wave * 1024;
  char* dB1 = (char*)B1s + wave * 1024;
  char* dB3 = (char*)B3s + wave * 1024;

  const int wm = wave >> 1, wn = wave & 1;
  const int l15 = lane & 15, kq = lane >> 4;
  const int c0 = (kq * 16) ^ ((l15 & 7) << 4);
  const int aoff = (wm * 64 + l15) * 128;
  const int boff = (wn * 64 + l15) * 128;

  f32x4 acc1[4][4] = {};
  f32x4 acc3[4][4] = {};

  for (int k0 = 0; k0 < KDIM; k0 += 64) {
    gload16(pA0, dA);                    gload16(pA1, dA + 4096);
    gload16(pA2, dA + 8192);             gload16(pA3, dA + 12288);
    gload16(pB0,                dB1);    gload16(pB0 +  32 * KDIM, dB1 + 4096);
    gload16(pB0 + 64 * KDIM,    dB1 + 8192); gload16(pB0 + 96 * KDIM, dB1 + 12288);
    gload16(pB0 + dW,           dB3);    gload16(pB0 + dW + 32 * KDIM, dB3 + 4096);
    gload16(pB0 + dW + 64 * KDIM, dB3 + 8192); gload16(pB0 + dW + 96 * KDIM, dB3 + 12288);
    pA0 += 64; pA1 += 64; pA2 += 64; pA3 += 64; pB0 += 64;
    __syncthreads();

#pragma unroll
    for (int h = 0; h < 2; h++) {
      const int ch = h ? (c0 ^ 64) : c0;
      bf16x8 af[4], bf[4];
#pragma unroll
      for (int i = 0; i < 4; i++)
        af[i] = *reinterpret_cast<const bf16x8*>((const char*)As + aoff + i * 2048 + ch);
#pragma unroll
      for (int i = 0; i < 4; i++)
        bf[i] = *reinterpret_cast<const bf16x8*>((const char*)B1s + boff + i * 2048 + ch);
#pragma unroll
      for (int mi = 0; mi < 4; mi++)
#pragma unroll
        for (int ni = 0; ni < 4; ni++)
          acc1[mi][ni] = __builtin_amdgcn_mfma_f32_16x16x32_bf16(af[mi], bf[ni], acc1[mi][ni], 0, 0, 0);
#pragma unroll
      for (int i = 0; i < 4; i++)
        bf[i] = *reinterpret_cast<const bf16x8*>((const char*)B3s + boff + i * 2048 + ch);
#pragma unroll
      for (int mi = 0; mi < 4; mi++)
#pragma unroll
        for (int ni = 0; ni < 4; ni++)
          acc3[mi][ni] = __builtin_amdgcn_mfma_f32_16x16x32_bf16(af[mi], bf[ni], acc3[mi][ni], 0, 0, 0);
    }
    __syncthreads();
  }

  const int slot0 = oe + mt * 128;
#pragma unroll
  for (int mi = 0; mi < 4; mi++) {
#pragma unroll
    for (int ni = 0; ni < 4; ni++) {
      const int coln = nt * 128 + wn * 64 + ni * 16 + l15;
#pragma unroll
      for (int r = 0; r < 4; r++) {
        const int lrow = wm * 64 + mi * 16 + kq * 4 + r;
        if (mt * 128 + lrow < Me) {
          float h1 = acc1[mi][ni][r];
          float h3 = acc3[mi][ni][r];
          float sig = 1.f / (1.f + __expf(-h1));
          act[(size_t)(slot0 + lrow) * KDIM + coln] = f2bf(h1 * sig * h3);
        }
      }
    }
  }
}

// ---------------- GEMM2: out[token] += rw * (act @ fc2), 128x128 tile, BK=64 ----------------
__global__ __launch_bounds__(256, 2)
void gemm2_kernel(const unsigned short* __restrict__ A,
                  const unsigned short* __restrict__ W,
                  const int* __restrict__ cnt, const int* __restrict__ ofs,
                  const int* __restrict__ brow, const float* __restrict__ bw,
                  float* __restrict__ out) {
  const int e = blockIdx.z, mt = blockIdx.y, nt = blockIdx.x;
  const int Me = cnt[e];
  if (mt * 128 >= Me) return;
  __shared__ unsigned short As[128 * 64];
  __shared__ unsigned short Bs[128 * 64];
  __shared__ int ridx[128];
  __shared__ float rww[128];
  const int t = threadIdx.x, lane = t & 63, wave = t >> 6;
  const int oe = ofs[e];
  if (t < 128) {
    int sl = mt * 128 + t;
    int ok = sl < Me;
    ridx[t] = ok ? brow[e * CAP + sl] : 0;
    rww[t] = ok ? bw[e * CAP + sl] : 0.f;
  }
  __syncthreads();

  const int srow = t >> 3;
  const int kg = ((t & 7) ^ (srow & 7)) * 8;
  int s;
  const unsigned short *pA0, *pA1, *pA2, *pA3;
  s = mt * 128 + srow +  0; if (s >= Me) s = 0; pA0 = A + (size_t)(oe + s) * KDIM + kg;
  s = mt * 128 + srow + 32; if (s >= Me) s = 0; pA1 = A + (size_t)(oe + s) * KDIM + kg;
  s = mt * 128 + srow + 64; if (s >= Me) s = 0; pA2 = A + (size_t)(oe + s) * KDIM + kg;
  s = mt * 128 + srow + 96; if (s >= Me) s = 0; pA3 = A + (size_t)(oe + s) * KDIM + kg;
  const unsigned short* pB0 = W + (size_t)e * KDIM * KDIM + (size_t)(nt * 128 + srow) * KDIM + kg;
  char* dA = (char*)As + wave * 1024;
  char* dB = (char*)Bs + wave * 1024;

  const int wm = wave >> 1, wn = wave & 1;
  const int l15 = lane & 15, kq = lane >> 4;
  const int c0 = (kq * 16) ^ ((l15 & 7) << 4);
  const int aoff = (wm * 64 + l15) * 128;
  const int boff = (wn * 64 + l15) * 128;

  f32x4 acc[4][4] = {};

  for (int k0 = 0; k0 < KDIM; k0 += 64) {
    gload16(pA0, dA);         gload16(pA1, dA + 4096);
    gload16(pA2, dA + 8192);  gload16(pA3, dA + 12288);
    gload16(pB0,             dB);        gload16(pB0 + 32 * KDIM, dB + 4096);
    gload16(pB0 + 64 * KDIM, dB + 8192); gload16(pB0 + 96 * KDIM, dB + 12288);
    pA0 += 64; pA1 += 64; pA2 += 64; pA3 += 64; pB0 += 64;
    __syncthreads();

#pragma unroll
    for (int h = 0; h < 2; h++) {
      const int ch = h ? (c0 ^ 64) : c0;
      bf16x8 af[4], bf[4];
#pragma unroll
      for (int i = 0; i < 4; i++) {
        af[i] = *reinterpret_cast<const bf16x8*>((const char*)As + aoff + i * 2048 + ch);
        bf[i] = *reinterpret_cast<const bf16x8*>((const char*)Bs + boff + i * 2048 + ch);
      }
#pragma unroll
      for (int mi = 0; mi < 4; mi++)
#pragma unroll
        for (int ni = 0; ni < 4; ni++)
          acc[mi][ni] = __builtin_amdgcn_mfma_f32_16x16x32_bf16(af[mi], bf[ni], acc[mi][ni], 0, 0, 0);
    }
    __syncthreads();
  }

#pragma unroll
  for (int mi = 0; mi < 4; mi++) {
#pragma unroll
    for (int ni = 0; ni < 4; ni++) {
      const int coln = nt * 128 + wn * 64 + ni * 16 + l15;
#pragma unroll
      for (int r = 0; r < 4; r++) {
        const int lrow = wm * 64 + mi * 16 + kq * 4 + r;
        if (mt * 128 + lrow < Me) {
          float v = acc[mi][ni][r] * rww[lrow];
          unsafeAtomicAdd(&out[(size_t)ridx[lrow] * HID + coln], v);
        }
      }
    }
  }
}

extern "C" void kernel_launch(void* const* d_in, const int* in_sizes, int n_in,
                              void* d_out, int out_size, void* d_ws, size_t ws_size,
                              hipStream_t stream) {
  const float* x     = (const float*)d_in[0];
  const float* probs = (const float*)d_in[1];
  const float* fc1   = (const float*)d_in[2];
  const float* fc2   = (const float*)d_in[3];
  const float* fc3   = (const float*)d_in[4];
  float* out = (float*)d_out;

  char* ws = (char*)d_ws;
  const size_t WSZ = (size_t)NEXP * HID * INTERN * 2;  // 64 MiB per weight tensor
  unsigned short* wt1 = (unsigned short*)(ws);
  unsigned short* wt3 = (unsigned short*)(ws + WSZ);
  unsigned short* wt2 = (unsigned short*)(ws + 2 * WSZ);
  unsigned short* act = (unsigned short*)(ws + 3 * WSZ);   // 16384 x 2048 bf16
  unsigned short* xb  = (unsigned short*)(ws + 4 * WSZ);   // 8192 x 2048 bf16
  char* rbase = ws + 4 * WSZ + (size_t)NROWS * HID * 2;
  int*   brow = (int*)  (rbase);
  float* bw   = (float*)(rbase + (size_t)NEXP * CAP * 4);
  int*   cnt  = (int*)  (rbase + 2 * (size_t)NEXP * CAP * 4);
  int*   ofs  = (int*)  (rbase + 2 * (size_t)NEXP * CAP * 4 + 64);

  hipMemsetAsync(d_out, 0, (size_t)out_size * sizeof(float), stream);
  hipMemsetAsync(cnt, 0, 64, stream);

  xcast_kernel<<<2048, 256, 0, stream>>>(x, xb);
  transpose_cast_kernel<<<dim3(32, 32, 8), 256, 0, stream>>>(fc1, wt1);
  transpose_cast_kernel<<<dim3(32, 32, 8), 256, 0, stream>>>(fc3, wt3);
  transpose_cast_kernel<<<dim3(32, 32, 8), 256, 0, stream>>>(fc2, wt2);
  router_kernel<<<NROWS / 256, 256, 0, stream>>>(probs, cnt, brow, bw);
  offsets_kernel<<<1, 64, 0, stream>>>(cnt, ofs);

  gemm13_kernel<<<dim3(INTERN / 128, CAP / 128, NEXP), 256, 0, stream>>>(xb, wt1, wt3, cnt, ofs, brow, act);
  gemm2_kernel<<<dim3(HID / 128, CAP / 128, NEXP), 256, 0, stream>>>(act, wt2, cnt, ofs, brow, bw, out);
}